// Round 3
// baseline (236.836 us; speedup 1.0000x reference)
//
#include <hip/hip_runtime.h>
#include <math.h>

#define WPB 4            // waves per block (block = 256 threads)
#define LDS_STRIDE 1184  // padded dwords per wave buffer (max padA(1023)=1183)

typedef float v4f __attribute__((ext_vector_type(4)));  // clang-native for NT store

// Padded LDS address for canonical element index i (0..1023).
// Multiples of 4 only -> float4 alignment preserved; every access pattern
// below lands at <=2 lanes/bank (the wave64 minimum -> free, m136).
__device__ __forceinline__ int padA(int i) {
    return i + ((i >> 5) << 2) + (((i >> 8) & 3) << 3) + (((i >> 6) & 3) << 2);
}

__global__ __launch_bounds__(256) void qel_butterfly(
    const float* __restrict__ x,
    const float* __restrict__ ang,   // [4][10][3]
    float* __restrict__ out,
    int rows)
{
    __shared__ __align__(16) float sm[WPB * LDS_STRIDE];
    const int tid  = threadIdx.x;
    const int wave = tid >> 6;
    const int lane = tid & 63;
    float* wsm = sm + wave * LDS_STRIDE;

    const int row = blockIdx.x * WPB + wave;
    if (row >= rows) return;

    const float* xr = x   + (size_t)row * 1024;
    float*       yr = out + (size_t)row * 1024;

    // ---- Issue global loads FIRST (one contiguous 1 KiB per instr);
    //      sincos/angle math below overlaps the ~900-cycle HBM latency.
    float4 L0 = *(const float4*)(xr +   0 + 4 * lane);
    float4 L1 = *(const float4*)(xr + 256 + 4 * lane);
    float4 L2 = *(const float4*)(xr + 512 + 4 * lane);
    float4 L3 = *(const float4*)(xr + 768 + 4 * lane);

    // Fused per-bit rotation: qubit n acts on bit b = 9-n,
    // theta_n = 0.5 * sum_{l,k} angles[l][n][k]  (layers + RzRyRx all fuse:
    // 2D rotations commute; cnot_matrix is the identity permutation).
    float cb[10], sb[10];
#pragma unroll
    for (int n = 0; n < 10; ++n) {
        float t = 0.f;
#pragma unroll
        for (int l = 0; l < 4; ++l) {
            const float* a = ang + (l * 10 + n) * 3;
            t += a[0] + a[1] + a[2];
        }
        t *= 0.5f;
        sincosf(t, &sb[9 - n], &cb[9 - n]);
    }

    float v[16];

// butterfly on local index bit P with rotation (CC,SS); "low" = bit==0
#define STAGE(P, CC, SS)                                        \
    do {                                                        \
        _Pragma("unroll")                                       \
        for (int q = 0; q < 16; ++q)                            \
            if ((q & (1 << (P))) == 0) {                        \
                float lo = v[q], hi = v[q | (1 << (P))];        \
                v[q]              = (CC) * lo - (SS) * hi;      \
                v[q | (1 << (P))] = (SS) * lo + (CC) * hi;      \
            }                                                   \
    } while (0)

    // ---- Phase A: lane holds i = 256*m + 4*lane + k  -> v[4m+k]
    v[0]=L0.x; v[1]=L0.y; v[2]=L0.z; v[3]=L0.w;
    v[4]=L1.x; v[5]=L1.y; v[6]=L1.z; v[7]=L1.w;
    v[8]=L2.x; v[9]=L2.y; v[10]=L2.z; v[11]=L2.w;
    v[12]=L3.x; v[13]=L3.y; v[14]=L3.z; v[15]=L3.w;

    STAGE(0, cb[0], sb[0]);   // global bit 0
    STAGE(1, cb[1], sb[1]);   // global bit 1
    STAGE(2, cb[8], sb[8]);   // global bit 8 (m bit 0)
    STAGE(3, cb[9], sb[9]);   // global bit 9 (m bit 1)

    // LDS transpose 1. DS ops from one wave execute in order in the LDS
    // pipe; backend inserts the lgkmcnt waits it needs (no barriers: each
    // wave owns its slice, one row per wave -> no WAR across iterations).
#pragma unroll
    for (int m = 0; m < 4; ++m)
        *(float4*)(wsm + padA(256 * m + 4 * lane)) =
            make_float4(v[4*m+0], v[4*m+1], v[4*m+2], v[4*m+3]);

    // ---- Phase B: lane holds i = 64*g + 4*j + t, g=lane>>2, t=lane&3
    {
        const int g = lane >> 2, t = lane & 3;
#pragma unroll
        for (int j = 0; j < 16; ++j)
            v[j] = wsm[padA(64 * g + 4 * j + t)];
        STAGE(0, cb[2], sb[2]);   // global bit 2
        STAGE(1, cb[3], sb[3]);   // global bit 3
        STAGE(2, cb[4], sb[4]);   // global bit 4
        STAGE(3, cb[5], sb[5]);   // global bit 5
#pragma unroll
        for (int j = 0; j < 16; ++j)
            wsm[padA(64 * g + 4 * j + t)] = v[j];
    }

    // ---- Phase C: lane holds i = 256*M + 64*h + 4*L, M=lane>>4, L=lane&15
    {
        const int M = lane >> 4, L = lane & 15;
#pragma unroll
        for (int h = 0; h < 4; ++h) {
            const float4 t4 = *(const float4*)(wsm + padA(256 * M + 64 * h + 4 * L));
            v[4*h+0] = t4.x; v[4*h+1] = t4.y; v[4*h+2] = t4.z; v[4*h+3] = t4.w;
        }
        STAGE(2, cb[6], sb[6]);   // global bit 6 (h bit 0)
        STAGE(3, cb[7], sb[7]);   // global bit 7 (h bit 1)
                                  // bits 0,1 (k) already rotated in Phase A
#pragma unroll
        for (int h = 0; h < 4; ++h) {
            v4f t4 = { v[4*h+0], v[4*h+1], v[4*h+2], v[4*h+3] };
            // write-once output: non-temporal keeps input resident in L3
            __builtin_nontemporal_store(t4, (v4f*)(yr + 256 * M + 64 * h + 4 * L));
        }
    }
#undef STAGE
}

extern "C" void kernel_launch(void* const* d_in, const int* in_sizes, int n_in,
                              void* d_out, int out_size, void* d_ws, size_t ws_size,
                              hipStream_t stream) {
    const float* x   = (const float*)d_in[0];
    const float* ang = (const float*)d_in[1];
    // d_in[2] (cnot_matrix) is provably the identity permutation -> unused.
    float* out = (float*)d_out;
    const int rows = in_sizes[0] / 1024;   // 32768
    const int blocks = (rows + WPB - 1) / WPB;  // one row per wave, no loop
    qel_butterfly<<<blocks, 256, 0, stream>>>(x, ang, out, rows);
}